// Round 8
// baseline (98.283 us; speedup 1.0000x reference)
//
#include <hip/hip_runtime.h>

typedef unsigned int u32;
typedef unsigned char u8;
typedef unsigned long long u64;

// Problem constants
#define DIMS   10000
#define LEVELS 100
#define SSIZE  617
#define SPAD   624        // padded s (rows 617..623 zero in idb, offw -> zero row)
#define NCLS   26
#define BATCH  32
#define WORDS  313        // ceil(10000/32) real sign-bit words per row
#define WPITCH 320        // padded word pitch; words 313..319 = 0
#define DPITCH 10240      // byte-count pitch per (slot,b) = WPITCH*32
#define NTILE  5          // d-tiles of 64 words (2048 dims)
#define NCH    13         // s-chunks of 48 (624 = 13*48); counts <= 48 <= 63 cap
#define CHUNK  48

// ws layout (bytes)
#define OFF_OFFW 0x000000u  // 624*32*4    =  79,872  (word offsets idx*WPITCH)
#define OFF_IDB  0x020000u  // 624*320*4   = 798,720
#define OFF_LVB  0x100000u  // 101*320*4   = 129,280  (row 100 = zeros, s-pad)
#define OFF_P8   0x140000u  // nch*32*10240 (13 slots = 4.3 MB)
#define SLOT_BYTES ((size_t)BATCH * DPITCH)   // 327,680

#define PK_ROWS (SPAD + LEVELS + 1)  // 725: id rows 0..623, lvl rows 0..100

// ---------------------------------------------------------------------------
// K1: sign-pack, fully coalesced. Grid (10, 725): block (g, r) covers dims
// [1024g, 1024g+1024) of row r. Thread t loads ONE float4 (16 B/lane), makes
// a sign nibble, LDS transpose, 32 threads emit words. id rows 617..623,
// lvl row 100, and pad words 313..319 all get zeros. Low flat-id blocks also
// quantize x -> lvb WORD offsets (transposed [s][b]) and zero d_out.
// ---------------------------------------------------------------------------
__global__ __launch_bounds__(256) void k_pack(const float* __restrict__ x,
                                              const float* __restrict__ idw,
                                              const float* __restrict__ lvw,
                                              u32* __restrict__ idb,
                                              u32* __restrict__ lvb,
                                              u32* __restrict__ offw,
                                              float* __restrict__ out)
{
    const int g = blockIdx.x;          // 0..9
    const int r = blockIdx.y;          // 0..724
    const int t = threadIdx.x;
    const bool isLvl = r >= SPAD;
    const int rl = r - SPAD;           // lvl row if isLvl
    const int d0 = g * 1024 + 4 * t;

    u32 nib = 0;
    const bool rowValid = isLvl ? (rl < LEVELS) : (r < SSIZE);
    if (d0 + 3 < DIMS && rowValid) {
        const float* src = isLvl ? (lvw + (size_t)rl * DIMS)
                                 : (idw + (size_t)r * DIMS);
        float4 f = *(const float4*)(src + d0);
        nib =  (__builtin_bit_cast(u32, f.x) >> 31)
            | ((__builtin_bit_cast(u32, f.y) >> 31) << 1)
            | ((__builtin_bit_cast(u32, f.z) >> 31) << 2)
            | ((__builtin_bit_cast(u32, f.w) >> 31) << 3);
    }
    __shared__ u32 nibs[256];
    nibs[t] = nib;
    __syncthreads();
    if (t < 32) {
        u32 w = 0;
#pragma unroll
        for (int j = 0; j < 8; ++j) w |= nibs[t * 8 + j] << (4 * j);
        u32* dst = isLvl ? (lvb + (size_t)rl * WPITCH)
                         : (idb + (size_t)r * WPITCH);
        dst[g * 32 + t] = w;           // g*32+t spans 0..319 = WPITCH
    }

    // Side work on the first 78+ blocks (flat id B = r*10+g).
    const int B = r * 10 + g;
    const int t2 = B * 256 + t;
    if (t2 < SPAD * BATCH) {
        int s = t2 >> 5, b = t2 & 31;
        u32 off = (u32)LEVELS * WPITCH;        // pad s -> zero lvb row 100
        if (s < SSIZE) {
            float v = x[b * SSIZE + s];
            float rr = rintf(v * (float)(LEVELS - 1));  // RTE = jnp.round
            int q = (int)rr;
            q = q < 0 ? 0 : (q > LEVELS - 1 ? LEVELS - 1 : q);
            off = (u32)q * WPITCH;             // lvb word offset of level row
        }
        offw[s * BATCH + b] = off;
    }
    if (t2 < BATCH * NCLS) out[t2] = 0.0f;
}

// ---------------------------------------------------------------------------
// Shared epilogue: 6 CSA planes -> u8 counts, 32 B per (b, word).
// bit j of plane -> byte j bit of count (nibble-spread by 0x00204081 mul).
// ---------------------------------------------------------------------------
__device__ __forceinline__ void spread6(u32* __restrict__ part,
                                        int slot, int B0, int wq,
                                        const u32 ones[4], const u32 c0[4],
                                        const u32 c1[4], const u32 c2[4],
                                        const u32 c3[4], const u32 c4[4])
{
#pragma unroll
    for (int b = 0; b < 4; ++b) {
        u32* dst = part + ((size_t)(slot * BATCH + B0 + b) * DPITCH + (size_t)wq * 32) / 4;
        u32 o[8];
#pragma unroll
        for (int g = 0; g < 8; ++g) {
            int sh = 4 * g;
            u32 n;
            n  =  (((ones[b] >> sh) & 0xFu) * 0x00204081u) & 0x01010101u;
            n |= ((((c0[b]  >> sh) & 0xFu) * 0x00204081u) & 0x01010101u) << 1;
            n |= ((((c1[b]  >> sh) & 0xFu) * 0x00204081u) & 0x01010101u) << 2;
            n |= ((((c2[b]  >> sh) & 0xFu) * 0x00204081u) & 0x01010101u) << 3;
            n |= ((((c3[b]  >> sh) & 0xFu) * 0x00204081u) & 0x01010101u) << 4;
            n |= ((((c4[b]  >> sh) & 0xFu) * 0x00204081u) & 0x01010101u) << 5;
            o[g] = n;
        }
        *(uint4*)(dst)     = make_uint4(o[0], o[1], o[2], o[3]);
        *(uint4*)(dst + 4) = make_uint4(o[4], o[5], o[6], o[7]);
    }
}

// ---------------------------------------------------------------------------
// K2: bit-sliced bind+count, NO LDS — level rows gathered straight from L2
// (lvb = 129 KB, resident in every XCD's L2). Block = ONE wave: 64 words
// (lane=word) x 4 batches (B0 = 4*blockIdx.y -> offsets scalar by
// construction) x CH s of one slot. All inner loads are VMEM (in-order,
// deep outstanding queue) — no ds_read/lgkmcnt entanglement, no barrier.
// 6 CSA planes (capacity 63 >= CH=48).
// ---------------------------------------------------------------------------
template <int CH>
__global__ __launch_bounds__(64) void k_bind_t(const u32* __restrict__ idb,
                                               const u32* __restrict__ lvb,
                                               const u32* __restrict__ offw,
                                               u32* __restrict__ part)
{
    const int wq   = blockIdx.x * 64 + threadIdx.x;   // word, < 320
    const int B0   = blockIdx.y * 4;                  // batch group (SGPR)
    const int slot = blockIdx.z;
    const int sBeg = slot * CH;

    u32 ones[4], c0[4], c1[4], c2[4], c3[4], c4[4];
#pragma unroll
    for (int b = 0; b < 4; ++b) { ones[b]=0; c0[b]=0; c1[b]=0; c2[b]=0; c3[b]=0; c4[b]=0; }

#pragma unroll
    for (int i = 0; i < CH / 2; ++i) {
        const int s = sBeg + 2 * i;
        u32 u1 = idb[(size_t)s * WPITCH + wq];        // coalesced 256 B
        u32 u2 = idb[(size_t)(s + 1) * WPITCH + wq];
        const u32* o1 = offw + s * BATCH + B0;        // scalar address
        const u32* o2 = o1 + BATCH;
#pragma unroll
        for (int b = 0; b < 4; ++b) {
            u32 l1 = lvb[o1[b] + wq];                 // L2-hit gather, 256 B
            u32 l2 = lvb[o2[b] + wq];
            u32 x1 = u1 ^ l1, x2 = u2 ^ l2;
            u32 t0 = x1 ^ x2;
            u32 sum = ones[b] ^ t0;
            u32 car = (x1 & x2) | (ones[b] & t0);
            ones[b] = sum;
            u32 tt;
            tt = c0[b] & car; c0[b] ^= car; car = tt;
            tt = c1[b] & car; c1[b] ^= car; car = tt;
            tt = c2[b] & car; c2[b] ^= car; car = tt;
            tt = c3[b] & car; c3[b] ^= car; car = tt;
            c4[b] ^= car;                             // counts <= 48 <= 63
        }
    }
    spread6(part, slot, B0, wq, ones, c0, c1, c2, c3, c4);
}

// Generic fallback (runtime chunk <= 62) — only for tiny ws.
__global__ __launch_bounds__(64) void k_bind_g(const u32* __restrict__ idb,
                                               const u32* __restrict__ lvb,
                                               const u32* __restrict__ offw,
                                               u32* __restrict__ part,
                                               int chunk)
{
    const int wq   = blockIdx.x * 64 + threadIdx.x;
    const int B0   = blockIdx.y * 4;
    const int slot = blockIdx.z;
    const int sBeg = slot * chunk;
    const int sEnd = min(SPAD, sBeg + chunk);

    u32 ones[4], c0[4], c1[4], c2[4], c3[4], c4[4];
#pragma unroll
    for (int b = 0; b < 4; ++b) { ones[b]=0; c0[b]=0; c1[b]=0; c2[b]=0; c3[b]=0; c4[b]=0; }

    for (int s = sBeg; s < sEnd; s += 2) {
        u32 u1 = idb[(size_t)s * WPITCH + wq];
        u32 u2 = idb[(size_t)(s + 1) * WPITCH + wq];
        const u32* o1 = offw + s * BATCH + B0;
        const u32* o2 = o1 + BATCH;
#pragma unroll
        for (int b = 0; b < 4; ++b) {
            u32 l1 = lvb[o1[b] + wq];
            u32 l2 = lvb[o2[b] + wq];
            u32 x1 = u1 ^ l1, x2 = u2 ^ l2;
            u32 t0 = x1 ^ x2;
            u32 sum = ones[b] ^ t0;
            u32 car = (x1 & x2) | (ones[b] & t0);
            ones[b] = sum;
            u32 tt;
            tt = c0[b] & car; c0[b] ^= car; car = tt;
            tt = c1[b] & car; c1[b] ^= car; car = tt;
            tt = c2[b] & car; c2[b] ^= car; car = tt;
            tt = c3[b] & car; c3[b] ^= car; car = tt;
            c4[b] ^= car;                             // capacity 63
        }
    }
    spread6(part, slot, B0, wq, ones, c0, c1, c2, c3, c4);
}

// ---------------------------------------------------------------------------
// K3 (fused enc+logit, compile-time nch): block (q,b) owns dims
// [1024q, 1024q+1024) of batch b. Thread = 1 dword = 4 dim-counts; all NCHT
// slot loads issued up-front (one latency round). u16-pair accumulate
// (max 13*48 = 624 < 65536). enc=+1 <=> count <= 308 (multiset = 617-2*count
// is odd -> never 0). Per-thread 4-dim dot with 26 W rows (coalesced
// float4), wave shuffle-reduce, LDS cross-wave, atomicAdd into zeroed out.
// ---------------------------------------------------------------------------
template <int NCHT>
__global__ __launch_bounds__(256) void k_encl_t(const u32* __restrict__ part,
                                                const float* __restrict__ W,
                                                float* __restrict__ out)
{
    const int b = blockIdx.y;
    const int q = blockIdx.x;
    const int t = threadIdx.x;
    const int dw = q * 256 + t;                 // dword index, < 2560
    const u32* p = part + (size_t)b * (DPITCH / 4) + dw;
    const size_t cs = (size_t)BATCH * (DPITCH / 4);

    u32 v[NCHT];
#pragma unroll
    for (int c = 0; c < NCHT; ++c) v[c] = p[(size_t)c * cs];  // all outstanding
    u32 a01 = 0, a23 = 0;
#pragma unroll
    for (int c = 0; c < NCHT; ++c) {
        a01 += v[c] & 0x00FF00FFu;
        a23 += (v[c] >> 8) & 0x00FF00FFu;
    }
    const float e0 = (int)(a01 & 0xFFFFu) <= 308 ? 1.0f : -1.0f;
    const float e1 = (int)(a23 & 0xFFFFu) <= 308 ? 1.0f : -1.0f;
    const float e2 = (int)(a01 >> 16)     <= 308 ? 1.0f : -1.0f;
    const float e3 = (int)(a23 >> 16)     <= 308 ? 1.0f : -1.0f;

    float acc[NCLS];
    if (dw < DIMS / 4) {
#pragma unroll
        for (int cc = 0; cc < NCLS; ++cc) {
            float4 w4 = *(const float4*)(W + (size_t)cc * DIMS + 4 * dw);
            acc[cc] = fmaf(e0, w4.x, fmaf(e1, w4.y, fmaf(e2, w4.z, e3 * w4.w)));
        }
    } else {
#pragma unroll
        for (int cc = 0; cc < NCLS; ++cc) acc[cc] = 0.0f;
    }

#pragma unroll
    for (int cc = 0; cc < NCLS; ++cc) {
#pragma unroll
        for (int o = 32; o > 0; o >>= 1)
            acc[cc] += __shfl_xor(acc[cc], o);
    }
    __shared__ float red[4][NCLS];
    const int lane = t & 63, wv = t >> 6;
    if (lane == 0) {
#pragma unroll
        for (int cc = 0; cc < NCLS; ++cc) red[wv][cc] = acc[cc];
    }
    __syncthreads();
    if (t < NCLS) {
        float vv = red[0][t] + red[1][t] + red[2][t] + red[3][t];
        atomicAdd(out + b * NCLS + t, vv);
    }
}

// Generic fallback (runtime nch).
__global__ __launch_bounds__(256) void k_encl_g(const u32* __restrict__ part,
                                                const float* __restrict__ W,
                                                float* __restrict__ out,
                                                int nch)
{
    const int b = blockIdx.y;
    const int q = blockIdx.x;
    const int t = threadIdx.x;
    const int dw = q * 256 + t;
    const u32* p = part + (size_t)b * (DPITCH / 4) + dw;
    const size_t cs = (size_t)BATCH * (DPITCH / 4);
    u32 a01 = 0, a23 = 0;
    for (int c = 0; c < nch; ++c) {
        u32 v = p[(size_t)c * cs];
        a01 += v & 0x00FF00FFu;
        a23 += (v >> 8) & 0x00FF00FFu;
    }
    const float e0 = (int)(a01 & 0xFFFFu) <= 308 ? 1.0f : -1.0f;
    const float e1 = (int)(a23 & 0xFFFFu) <= 308 ? 1.0f : -1.0f;
    const float e2 = (int)(a01 >> 16)     <= 308 ? 1.0f : -1.0f;
    const float e3 = (int)(a23 >> 16)     <= 308 ? 1.0f : -1.0f;
    float acc[NCLS];
    if (dw < DIMS / 4) {
#pragma unroll
        for (int cc = 0; cc < NCLS; ++cc) {
            float4 w4 = *(const float4*)(W + (size_t)cc * DIMS + 4 * dw);
            acc[cc] = fmaf(e0, w4.x, fmaf(e1, w4.y, fmaf(e2, w4.z, e3 * w4.w)));
        }
    } else {
#pragma unroll
        for (int cc = 0; cc < NCLS; ++cc) acc[cc] = 0.0f;
    }
#pragma unroll
    for (int cc = 0; cc < NCLS; ++cc) {
#pragma unroll
        for (int o = 32; o > 0; o >>= 1)
            acc[cc] += __shfl_xor(acc[cc], o);
    }
    __shared__ float red[4][NCLS];
    const int lane = t & 63, wv = t >> 6;
    if (lane == 0) {
#pragma unroll
        for (int cc = 0; cc < NCLS; ++cc) red[wv][cc] = acc[cc];
    }
    __syncthreads();
    if (t < NCLS) {
        float vv = red[0][t] + red[1][t] + red[2][t] + red[3][t];
        atomicAdd(out + b * NCLS + t, vv);
    }
}

// ---------------------------------------------------------------------------
extern "C" void kernel_launch(void* const* d_in, const int* in_sizes, int n_in,
                              void* d_out, int out_size, void* d_ws, size_t ws_size,
                              hipStream_t stream)
{
    const float* x   = (const float*)d_in[0];  // (32, 617)
    const float* idw = (const float*)d_in[1];  // (617, 10000)
    const float* lvw = (const float*)d_in[2];  // (100, 10000)
    const float* W   = (const float*)d_in[3];  // (26, 10000)
    float* out = (float*)d_out;                // (32, 26)

    char* ws = (char*)d_ws;
    u32* offw = (u32*)(ws + OFF_OFFW);
    u32* idb  = (u32*)(ws + OFF_IDB);
    u32* lvb  = (u32*)(ws + OFF_LVB);
    u32* part = (u32*)(ws + OFF_P8);

    size_t avail = ws_size > OFF_P8 ? ws_size - OFF_P8 : 0;
    const bool fast = avail >= (size_t)NCH * SLOT_BYTES;   // always true @256MiB

    dim3 g1(10, PK_ROWS);                      // 7250 blocks
    k_pack<<<g1, 256, 0, stream>>>(x, idw, lvw, idb, lvb, offw, out);

    if (fast) {
        dim3 g2(NTILE, 8, NCH);                // (5, 8, 13) = 520 wave-blocks
        k_bind_t<CHUNK><<<g2, 64, 0, stream>>>(idb, lvb, offw, part);
        dim3 g3(10, BATCH);                    // 320 blocks
        k_encl_t<NCH><<<g3, 256, 0, stream>>>(part, W, out);
    } else {
        int nch = (int)(avail / SLOT_BYTES);
        if (nch < 1) nch = 1;
        int chunk = (SPAD + nch - 1) / nch;
        chunk = (chunk + 1) & ~1;
        if (chunk > 62) chunk = 62;            // 6-plane CSA capacity bound
        nch = (SPAD + chunk - 1) / chunk;
        dim3 g2(NTILE, 8, nch);
        k_bind_g<<<g2, 64, 0, stream>>>(idb, lvb, offw, part, chunk);
        dim3 g3(10, BATCH);
        k_encl_g<<<g3, 256, 0, stream>>>(part, W, out, nch);
    }
}

// Round 9
// 90.998 us; speedup vs baseline: 1.0801x; 1.0801x over previous
//
#include <hip/hip_runtime.h>

typedef unsigned int u32;
typedef unsigned char u8;
typedef unsigned long long u64;

// Problem constants
#define DIMS   10000
#define LEVELS 100
#define SSIZE  617
#define SPAD   624        // padded s (rows 617..623 zero in idb; offsets -> zero row)
#define NCLS   26
#define BATCH  32
#define WORDS  313        // ceil(10000/32) real sign-bit words per row
#define WPITCH 320        // padded word pitch; words 313..319 = 0
#define DPITCH 10240      // byte-count pitch per (slot,b) = WPITCH*32
#define NTILE  5          // d-tiles of 64 words (2048 dims)
#define NCH    13         // s-chunks of 48 (624 = 13*48); counts <= 48 <= 63 cap
#define CHUNK  48
#define SOPITCH 640       // offt row pitch per batch (s padded 624 -> 640)

// ws layout (bytes)
#define OFF_OFFT 0x000000u  // 32*640*4    =  81,920  (offt[b][s] word offsets)
#define OFF_IDB  0x020000u  // 624*320*4   = 798,720
#define OFF_LVB  0x100000u  // 101*320*4   = 129,280  (row 100 = zeros, s-pad)
#define OFF_P8   0x140000u  // nch*32*10240 (13 slots = 4.3 MB)
#define SLOT_BYTES ((size_t)BATCH * DPITCH)   // 327,680

#define PK_ROWS (SPAD + LEVELS + 1)  // 725: id rows 0..623, lvl rows 0..100

// ---------------------------------------------------------------------------
// K1: sign-pack, fully coalesced. Grid (10, 725): block (g, r) covers dims
// [1024g, 1024g+1024) of row r. Thread t loads ONE float4 (16 B/lane), makes
// a sign nibble, LDS transpose, 32 threads emit words. id rows 617..623,
// lvl row 100, and pad words 313..319 all get zeros. Low flat-id blocks also
// quantize x -> lvb WORD offsets, stored TRANSPOSED offt[b][s] so one wave's
// 48 per-s offsets in k_bind are contiguous scalar loads. Also zero d_out.
// ---------------------------------------------------------------------------
__global__ __launch_bounds__(256) void k_pack(const float* __restrict__ x,
                                              const float* __restrict__ idw,
                                              const float* __restrict__ lvw,
                                              u32* __restrict__ idb,
                                              u32* __restrict__ lvb,
                                              u32* __restrict__ offt,
                                              float* __restrict__ out)
{
    const int g = blockIdx.x;          // 0..9
    const int r = blockIdx.y;          // 0..724
    const int t = threadIdx.x;
    const bool isLvl = r >= SPAD;
    const int rl = r - SPAD;           // lvl row if isLvl
    const int d0 = g * 1024 + 4 * t;

    u32 nib = 0;
    const bool rowValid = isLvl ? (rl < LEVELS) : (r < SSIZE);
    if (d0 + 3 < DIMS && rowValid) {
        const float* src = isLvl ? (lvw + (size_t)rl * DIMS)
                                 : (idw + (size_t)r * DIMS);
        float4 f = *(const float4*)(src + d0);
        nib =  (__builtin_bit_cast(u32, f.x) >> 31)
            | ((__builtin_bit_cast(u32, f.y) >> 31) << 1)
            | ((__builtin_bit_cast(u32, f.z) >> 31) << 2)
            | ((__builtin_bit_cast(u32, f.w) >> 31) << 3);
    }
    __shared__ u32 nibs[256];
    nibs[t] = nib;
    __syncthreads();
    if (t < 32) {
        u32 w = 0;
#pragma unroll
        for (int j = 0; j < 8; ++j) w |= nibs[t * 8 + j] << (4 * j);
        u32* dst = isLvl ? (lvb + (size_t)rl * WPITCH)
                         : (idb + (size_t)r * WPITCH);
        dst[g * 32 + t] = w;           // g*32+t spans 0..319 = WPITCH
    }

    // Side work on the first 78+ blocks (flat id B = r*10+g).
    const int B = r * 10 + g;
    const int t2 = B * 256 + t;
    if (t2 < SPAD * BATCH) {
        int s = t2 >> 5, b = t2 & 31;
        u32 off = (u32)LEVELS * WPITCH;        // pad s -> zero lvb row 100
        if (s < SSIZE) {
            float v = x[b * SSIZE + s];
            float rr = rintf(v * (float)(LEVELS - 1));  // RTE = jnp.round
            int q = (int)rr;
            q = q < 0 ? 0 : (q > LEVELS - 1 ? LEVELS - 1 : q);
            off = (u32)q * WPITCH;             // lvb word offset of level row
        }
        offt[b * SOPITCH + s] = off;           // TRANSPOSED [b][s]
    }
    if (t2 < BATCH * NCLS) out[t2] = 0.0f;
}

// ---------------------------------------------------------------------------
// CSA full-adder step into 6 bit-planes (capacity 63).
// ---------------------------------------------------------------------------
#define CSA6(xv)                                                              \
    {                                                                         \
        u32 car = ones & (xv);                                                \
        ones ^= (xv);                                                         \
        u32 tt;                                                               \
        tt = c0 & car; c0 ^= car; car = tt;                                   \
        tt = c1 & car; c1 ^= car; car = tt;                                   \
        tt = c2 & car; c2 ^= car; car = tt;                                   \
        tt = c3 & car; c3 ^= car; car = tt;                                   \
        c4 ^= car;                                                            \
    }

// ---------------------------------------------------------------------------
// Shared epilogue: 6 CSA planes -> u8 counts, 32 B per (b, word).
// bit j of plane -> byte j bit of count (nibble-spread by 0x00204081 mul).
// ---------------------------------------------------------------------------
__device__ __forceinline__ void spread6_1(u32* __restrict__ part,
                                          int slot, int b, int wq,
                                          u32 ones, u32 c0, u32 c1,
                                          u32 c2, u32 c3, u32 c4)
{
    u32* dst = part + ((size_t)(slot * BATCH + b) * DPITCH + (size_t)wq * 32) / 4;
    u32 o[8];
#pragma unroll
    for (int g = 0; g < 8; ++g) {
        int sh = 4 * g;
        u32 n;
        n  =  (((ones >> sh) & 0xFu) * 0x00204081u) & 0x01010101u;
        n |= ((((c0   >> sh) & 0xFu) * 0x00204081u) & 0x01010101u) << 1;
        n |= ((((c1   >> sh) & 0xFu) * 0x00204081u) & 0x01010101u) << 2;
        n |= ((((c2   >> sh) & 0xFu) * 0x00204081u) & 0x01010101u) << 3;
        n |= ((((c3   >> sh) & 0xFu) * 0x00204081u) & 0x01010101u) << 4;
        n |= ((((c4   >> sh) & 0xFu) * 0x01010101u) & 0x01010101u) << 5;
        o[g] = n;
    }
    // NOTE: the c4 line above must use the same 0x00204081 spread constant.
    // (kept identical below — see corrected write)
#pragma unroll
    for (int g = 0; g < 8; ++g) {
        int sh = 4 * g;
        u32 n;
        n  =  (((ones >> sh) & 0xFu) * 0x00204081u) & 0x01010101u;
        n |= ((((c0   >> sh) & 0xFu) * 0x00204081u) & 0x01010101u) << 1;
        n |= ((((c1   >> sh) & 0xFu) * 0x00204081u) & 0x01010101u) << 2;
        n |= ((((c2   >> sh) & 0xFu) * 0x00204081u) & 0x01010101u) << 3;
        n |= ((((c3   >> sh) & 0xFu) * 0x00204081u) & 0x01010101u) << 4;
        n |= ((((c4   >> sh) & 0xFu) * 0x00204081u) & 0x01010101u) << 5;
        o[g] = n;
    }
    *(uint4*)(dst)     = make_uint4(o[0], o[1], o[2], o[3]);
    *(uint4*)(dst + 4) = make_uint4(o[4], o[5], o[6], o[7]);
}

// ---------------------------------------------------------------------------
// K2: bit-sliced bind+count, latency-optimized. ONE wave per block, ONE batch
// per wave: grid (5 tiles, 32 b, 13 slots) = 2080 waves (~2/SIMD device-wide).
// Offsets: 48 contiguous scalar words from offt[b] (s_load_dwordx16 x3, one
// wait). Inner: 3 groups of 16 s — 32 VMEM loads issued into explicit arrays
// (all outstanding, single vmcnt wait), then 16 pure-VALU CSA steps into 6
// planes (capacity 63 >= 48). No LDS, no barrier, no lgkm/vmcnt mixing in
// the steady state. lvb (129 KB) + idb (798 KB) live in every XCD's L2.
// ---------------------------------------------------------------------------
template <int CH>
__global__ __launch_bounds__(64) void k_bind_t(const u32* __restrict__ idb,
                                               const u32* __restrict__ lvb,
                                               const u32* __restrict__ offt,
                                               u32* __restrict__ part)
{
    const int wq   = blockIdx.x * 64 + threadIdx.x;   // word, < 320
    const int b    = blockIdx.y;                      // batch (SGPR)
    const int slot = blockIdx.z;
    const int sBeg = slot * CH;

    // 48 offsets, contiguous in offt[b] -> scalar dwordx16 loads.
    u32 off[CH];
#pragma unroll
    for (int k = 0; k < CH; ++k) off[k] = offt[b * SOPITCH + sBeg + k];

    u32 ones = 0, c0 = 0, c1 = 0, c2 = 0, c3 = 0, c4 = 0;

#pragma unroll
    for (int grp = 0; grp < CH / 16; ++grp) {
        u32 u[16], l[16];
#pragma unroll
        for (int k = 0; k < 16; ++k) {
            const int s = sBeg + grp * 16 + k;
            u[k] = idb[(size_t)s * WPITCH + wq];      // coalesced 256 B
            l[k] = lvb[off[grp * 16 + k] + wq];       // L2 gather, 256 B
        }
#pragma unroll
        for (int k = 0; k < 16; ++k) {
            u32 xv = u[k] ^ l[k];
            CSA6(xv);
        }
    }
    spread6_1(part, slot, b, wq, ones, c0, c1, c2, c3, c4);
}

// Generic fallback (runtime chunk <= 62) — only for tiny ws.
__global__ __launch_bounds__(64) void k_bind_g(const u32* __restrict__ idb,
                                               const u32* __restrict__ lvb,
                                               const u32* __restrict__ offt,
                                               u32* __restrict__ part,
                                               int chunk)
{
    const int wq   = blockIdx.x * 64 + threadIdx.x;
    const int b    = blockIdx.y;
    const int slot = blockIdx.z;
    const int sBeg = slot * chunk;
    const int sEnd = min(SPAD, sBeg + chunk);

    u32 ones = 0, c0 = 0, c1 = 0, c2 = 0, c3 = 0, c4 = 0;
    for (int s = sBeg; s < sEnd; ++s) {
        u32 u1 = idb[(size_t)s * WPITCH + wq];
        u32 l1 = lvb[offt[b * SOPITCH + s] + wq];
        u32 xv = u1 ^ l1;
        CSA6(xv);
    }
    spread6_1(part, slot, b, wq, ones, c0, c1, c2, c3, c4);
}

// ---------------------------------------------------------------------------
// K3 (fused enc+logit, compile-time nch): block (q,b) owns dims
// [1024q, 1024q+1024) of batch b. Thread = 1 dword = 4 dim-counts; all NCHT
// slot loads issued up-front (one latency round). u16-pair accumulate
// (max 13*48 = 624 < 65536). enc=+1 <=> count <= 308 (multiset = 617-2*count
// is odd -> never 0). Per-thread 4-dim dot with 26 W rows (coalesced
// float4), wave shuffle-reduce, LDS cross-wave, atomicAdd into zeroed out.
// ---------------------------------------------------------------------------
template <int NCHT>
__global__ __launch_bounds__(256) void k_encl_t(const u32* __restrict__ part,
                                                const float* __restrict__ W,
                                                float* __restrict__ out)
{
    const int b = blockIdx.y;
    const int q = blockIdx.x;
    const int t = threadIdx.x;
    const int dw = q * 256 + t;                 // dword index, < 2560
    const u32* p = part + (size_t)b * (DPITCH / 4) + dw;
    const size_t cs = (size_t)BATCH * (DPITCH / 4);

    u32 v[NCHT];
#pragma unroll
    for (int c = 0; c < NCHT; ++c) v[c] = p[(size_t)c * cs];  // all outstanding
    u32 a01 = 0, a23 = 0;
#pragma unroll
    for (int c = 0; c < NCHT; ++c) {
        a01 += v[c] & 0x00FF00FFu;
        a23 += (v[c] >> 8) & 0x00FF00FFu;
    }
    const float e0 = (int)(a01 & 0xFFFFu) <= 308 ? 1.0f : -1.0f;
    const float e1 = (int)(a23 & 0xFFFFu) <= 308 ? 1.0f : -1.0f;
    const float e2 = (int)(a01 >> 16)     <= 308 ? 1.0f : -1.0f;
    const float e3 = (int)(a23 >> 16)     <= 308 ? 1.0f : -1.0f;

    float acc[NCLS];
    if (dw < DIMS / 4) {
#pragma unroll
        for (int cc = 0; cc < NCLS; ++cc) {
            float4 w4 = *(const float4*)(W + (size_t)cc * DIMS + 4 * dw);
            acc[cc] = fmaf(e0, w4.x, fmaf(e1, w4.y, fmaf(e2, w4.z, e3 * w4.w)));
        }
    } else {
#pragma unroll
        for (int cc = 0; cc < NCLS; ++cc) acc[cc] = 0.0f;
    }

#pragma unroll
    for (int cc = 0; cc < NCLS; ++cc) {
#pragma unroll
        for (int o = 32; o > 0; o >>= 1)
            acc[cc] += __shfl_xor(acc[cc], o);
    }
    __shared__ float red[4][NCLS];
    const int lane = t & 63, wv = t >> 6;
    if (lane == 0) {
#pragma unroll
        for (int cc = 0; cc < NCLS; ++cc) red[wv][cc] = acc[cc];
    }
    __syncthreads();
    if (t < NCLS) {
        float vv = red[0][t] + red[1][t] + red[2][t] + red[3][t];
        atomicAdd(out + b * NCLS + t, vv);
    }
}

// Generic fallback (runtime nch).
__global__ __launch_bounds__(256) void k_encl_g(const u32* __restrict__ part,
                                                const float* __restrict__ W,
                                                float* __restrict__ out,
                                                int nch)
{
    const int b = blockIdx.y;
    const int q = blockIdx.x;
    const int t = threadIdx.x;
    const int dw = q * 256 + t;
    const u32* p = part + (size_t)b * (DPITCH / 4) + dw;
    const size_t cs = (size_t)BATCH * (DPITCH / 4);
    u32 a01 = 0, a23 = 0;
    for (int c = 0; c < nch; ++c) {
        u32 v = p[(size_t)c * cs];
        a01 += v & 0x00FF00FFu;
        a23 += (v >> 8) & 0x00FF00FFu;
    }
    const float e0 = (int)(a01 & 0xFFFFu) <= 308 ? 1.0f : -1.0f;
    const float e1 = (int)(a23 & 0xFFFFu) <= 308 ? 1.0f : -1.0f;
    const float e2 = (int)(a01 >> 16)     <= 308 ? 1.0f : -1.0f;
    const float e3 = (int)(a23 >> 16)     <= 308 ? 1.0f : -1.0f;
    float acc[NCLS];
    if (dw < DIMS / 4) {
#pragma unroll
        for (int cc = 0; cc < NCLS; ++cc) {
            float4 w4 = *(const float4*)(W + (size_t)cc * DIMS + 4 * dw);
            acc[cc] = fmaf(e0, w4.x, fmaf(e1, w4.y, fmaf(e2, w4.z, e3 * w4.w)));
        }
    } else {
#pragma unroll
        for (int cc = 0; cc < NCLS; ++cc) acc[cc] = 0.0f;
    }
#pragma unroll
    for (int cc = 0; cc < NCLS; ++cc) {
#pragma unroll
        for (int o = 32; o > 0; o >>= 1)
            acc[cc] += __shfl_xor(acc[cc], o);
    }
    __shared__ float red[4][NCLS];
    const int lane = t & 63, wv = t >> 6;
    if (lane == 0) {
#pragma unroll
        for (int cc = 0; cc < NCLS; ++cc) red[wv][cc] = acc[cc];
    }
    __syncthreads();
    if (t < NCLS) {
        float vv = red[0][t] + red[1][t] + red[2][t] + red[3][t];
        atomicAdd(out + b * NCLS + t, vv);
    }
}

// ---------------------------------------------------------------------------
extern "C" void kernel_launch(void* const* d_in, const int* in_sizes, int n_in,
                              void* d_out, int out_size, void* d_ws, size_t ws_size,
                              hipStream_t stream)
{
    const float* x   = (const float*)d_in[0];  // (32, 617)
    const float* idw = (const float*)d_in[1];  // (617, 10000)
    const float* lvw = (const float*)d_in[2];  // (100, 10000)
    const float* W   = (const float*)d_in[3];  // (26, 10000)
    float* out = (float*)d_out;                // (32, 26)

    char* ws = (char*)d_ws;
    u32* offt = (u32*)(ws + OFF_OFFT);
    u32* idb  = (u32*)(ws + OFF_IDB);
    u32* lvb  = (u32*)(ws + OFF_LVB);
    u32* part = (u32*)(ws + OFF_P8);

    size_t avail = ws_size > OFF_P8 ? ws_size - OFF_P8 : 0;
    const bool fast = avail >= (size_t)NCH * SLOT_BYTES;   // always true @256MiB

    dim3 g1(10, PK_ROWS);                      // 7250 blocks
    k_pack<<<g1, 256, 0, stream>>>(x, idw, lvw, idb, lvb, offt, out);

    if (fast) {
        dim3 g2(NTILE, BATCH, NCH);            // (5, 32, 13) = 2080 wave-blocks
        k_bind_t<CHUNK><<<g2, 64, 0, stream>>>(idb, lvb, offt, part);
        dim3 g3(10, BATCH);                    // 320 blocks
        k_encl_t<NCH><<<g3, 256, 0, stream>>>(part, W, out);
    } else {
        int nch = (int)(avail / SLOT_BYTES);
        if (nch < 1) nch = 1;
        int chunk = (SPAD + nch - 1) / nch;
        if (chunk > 62) chunk = 62;            // 6-plane CSA capacity bound
        nch = (SPAD + chunk - 1) / chunk;
        dim3 g2(NTILE, BATCH, nch);
        k_bind_g<<<g2, 64, 0, stream>>>(idb, lvb, offt, part, chunk);
        dim3 g3(10, BATCH);
        k_encl_g<<<g3, 256, 0, stream>>>(part, W, out, nch);
    }
}